// Round 1
// baseline (4398.851 us; speedup 1.0000x reference)
//
#include <hip/hip_runtime.h>
#include <math.h>

#define NN 1024
#define BB 4
#define HH 8
#define DD 256
#define LL 4
#define DKK 32
#define MM 4096
#define EPSF 1e-6f

// ---------------------------------------------------------------------------
// Prologue: h[b,n,:] = x + in_deg_emb[deg_in[n]] + out_deg_emb[deg_out[n]]
//                    + pos[n,:] @ W_svd + b_svd, pos = [svd[:, :16], -svd[:,16:]]
// ---------------------------------------------------------------------------
__global__ __launch_bounds__(256) void prologue_kernel(
    const float* __restrict__ x, const int* __restrict__ deg_in,
    const int* __restrict__ deg_out, const float* __restrict__ svd,
    const float* __restrict__ in_emb, const float* __restrict__ out_emb,
    const float* __restrict__ Wsvd, const float* __restrict__ bsvd,
    float* __restrict__ h)
{
    int blk = blockIdx.x;            // b*N + n
    int n = blk & (NN - 1);
    int d = threadIdx.x;
    __shared__ float pos[32];
    if (d < 32) {
        float v = svd[n * 32 + d];
        pos[d] = (d < 16) ? v : -v;
    }
    __syncthreads();
    int di = deg_in[n], dо = deg_out[n];
    float acc = x[(size_t)blk * DD + d] + in_emb[(size_t)di * DD + d]
              + out_emb[(size_t)dо * DD + d] + bsvd[d];
#pragma unroll
    for (int j = 0; j < 32; ++j) acc += pos[j] * Wsvd[j * DD + d];
    h[(size_t)blk * DD + d] = acc;
}

// ---------------------------------------------------------------------------
// Spatial bias gather: bias[h][q][k] = spatial_emb[spatial_pos[q][k]][h]
// ---------------------------------------------------------------------------
__global__ __launch_bounds__(256) void bias_gather_kernel(
    const int* __restrict__ sp, const float* __restrict__ emb,
    float* __restrict__ bias)
{
    size_t idx = (size_t)blockIdx.x * 256 + threadIdx.x;   // q*N + k
    int p = sp[idx];
#pragma unroll
    for (int hh = 0; hh < HH; ++hh)
        bias[(size_t)hh * NN * NN + idx] = emb[p * HH + hh];
}

// ---------------------------------------------------------------------------
// Tiled fp32 GEMM  C[M,256] = A[M,256] @ W[256,256] + bias, optional ReLU.
// BM=BN=64, BK=16, 256 threads, 4x4 per thread.
// ---------------------------------------------------------------------------
template <int RELU>
__global__ __launch_bounds__(256) void gemm_linear_kernel(
    const float* __restrict__ A, const float* __restrict__ W,
    const float* __restrict__ bias, float* __restrict__ C)
{
    __shared__ float As[16][68];
    __shared__ float Bs[16][68];
    int tid = threadIdx.x;
    int tx = tid & 15, ty = tid >> 4;
    int m0 = blockIdx.x * 64;
    int n0 = blockIdx.y * 64;
    float acc[4][4] = {};
    for (int k0 = 0; k0 < 256; k0 += 16) {
#pragma unroll
        for (int i = 0; i < 4; ++i) {
            int idx = i * 256 + tid;
            int m = idx >> 4, kk = idx & 15;
            As[kk][m] = A[(size_t)(m0 + m) * DD + k0 + kk];
        }
#pragma unroll
        for (int i = 0; i < 4; ++i) {
            int idx = i * 256 + tid;
            int kk = idx >> 6, n = idx & 63;
            Bs[kk][n] = W[(size_t)(k0 + kk) * DD + n0 + n];
        }
        __syncthreads();
#pragma unroll
        for (int kk = 0; kk < 16; ++kk) {
            float4 a4 = *(const float4*)&As[kk][ty * 4];
            float4 b4 = *(const float4*)&Bs[kk][tx * 4];
            float av[4] = {a4.x, a4.y, a4.z, a4.w};
            float bv[4] = {b4.x, b4.y, b4.z, b4.w};
#pragma unroll
            for (int i = 0; i < 4; ++i)
#pragma unroll
                for (int j = 0; j < 4; ++j) acc[i][j] += av[i] * bv[j];
        }
        __syncthreads();
    }
#pragma unroll
    for (int i = 0; i < 4; ++i) {
        int m = m0 + ty * 4 + i;
#pragma unroll
        for (int j = 0; j < 4; ++j) {
            int n = n0 + tx * 4 + j;
            float v = acc[i][j] + bias[n];
            if (RELU) v = fmaxf(v, 0.f);
            C[(size_t)m * DD + n] = v;
        }
    }
}

// ---------------------------------------------------------------------------
// QKV GEMM: z in {0,1,2} picks {Wq,Wk,Wv}; output layout [B,H,N,DK].
// ---------------------------------------------------------------------------
__global__ __launch_bounds__(256) void gemm_qkv_kernel(
    const float* __restrict__ A,
    const float* __restrict__ Wq, const float* __restrict__ Wk,
    const float* __restrict__ Wv,
    const float* __restrict__ bq, const float* __restrict__ bk,
    const float* __restrict__ bv,
    float* __restrict__ qo, float* __restrict__ ko, float* __restrict__ vo)
{
    int z = blockIdx.z;
    const float* W = (z == 0) ? Wq : (z == 1) ? Wk : Wv;
    const float* bs = (z == 0) ? bq : (z == 1) ? bk : bv;
    float* out = (z == 0) ? qo : (z == 1) ? ko : vo;

    __shared__ float As[16][68];
    __shared__ float Bs[16][68];
    int tid = threadIdx.x;
    int tx = tid & 15, ty = tid >> 4;
    int m0 = blockIdx.x * 64;
    int n0 = blockIdx.y * 64;
    float acc[4][4] = {};
    for (int k0 = 0; k0 < 256; k0 += 16) {
#pragma unroll
        for (int i = 0; i < 4; ++i) {
            int idx = i * 256 + tid;
            int m = idx >> 4, kk = idx & 15;
            As[kk][m] = A[(size_t)(m0 + m) * DD + k0 + kk];
        }
#pragma unroll
        for (int i = 0; i < 4; ++i) {
            int idx = i * 256 + tid;
            int kk = idx >> 6, n = idx & 63;
            Bs[kk][n] = W[(size_t)(k0 + kk) * DD + n0 + n];
        }
        __syncthreads();
#pragma unroll
        for (int kk = 0; kk < 16; ++kk) {
            float4 a4 = *(const float4*)&As[kk][ty * 4];
            float4 b4 = *(const float4*)&Bs[kk][tx * 4];
            float av[4] = {a4.x, a4.y, a4.z, a4.w};
            float bv[4] = {b4.x, b4.y, b4.z, b4.w};
#pragma unroll
            for (int i = 0; i < 4; ++i)
#pragma unroll
                for (int j = 0; j < 4; ++j) acc[i][j] += av[i] * bv[j];
        }
        __syncthreads();
    }
#pragma unroll
    for (int i = 0; i < 4; ++i) {
        int m = m0 + ty * 4 + i;
        int b = m >> 10, n = m & (NN - 1);
#pragma unroll
        for (int j = 0; j < 4; ++j) {
            int nc = n0 + tx * 4 + j;
            int head = nc >> 5, dk = nc & 31;
            float v = acc[i][j] + bs[nc];
            out[(((size_t)b * HH + head) * NN + n) * DKK + dk] = v;
        }
    }
}

// ---------------------------------------------------------------------------
// Flash-style attention. q,k,v: [B,H,N,DK]; bias: [H,N,N]; o: [B,N,D].
// Block: 256 thr = 4 waves; 32 Q rows per block (8 per wave); K/V tiles of 64.
// ---------------------------------------------------------------------------
__global__ __launch_bounds__(256) void attn_kernel(
    const float* __restrict__ q, const float* __restrict__ k,
    const float* __restrict__ v, const float* __restrict__ bias,
    float* __restrict__ o)
{
    int bh = blockIdx.y;
    int b = bh >> 3, hh = bh & 7;
    int q0 = blockIdx.x * 32;
    int tid = threadIdx.x;
    int wave = tid >> 6, lane = tid & 63;

    __shared__ float Qs[32][33];
    __shared__ float Ks[64][33];
    __shared__ float Vs[64][33];
    __shared__ float ps[4][64];

    const size_t base = (size_t)bh * NN * DKK;
#pragma unroll
    for (int i = 0; i < 4; ++i) {
        int idx = i * 256 + tid;
        Qs[idx >> 5][idx & 31] = q[base + (size_t)q0 * DKK + idx];
    }
    float m_i[8], l_i[8], O_i[8];
#pragma unroll
    for (int r = 0; r < 8; ++r) { m_i[r] = -1e30f; l_i[r] = 0.f; O_i[r] = 0.f; }
    int d = lane & 31, kh = (lane >> 5) << 5;
    const float scale = 0.17677669529663687f;   // 1/sqrt(32)

    for (int kt = 0; kt < NN; kt += 64) {
        __syncthreads();
#pragma unroll
        for (int i = 0; i < 8; ++i) {
            int idx = i * 256 + tid;
            int rr = idx >> 5, jj = idx & 31;
            Ks[rr][jj] = k[base + (size_t)kt * DKK + idx];
            Vs[rr][jj] = v[base + (size_t)kt * DKK + idx];
        }
        __syncthreads();
        const float* brow = &bias[((size_t)hh * NN + q0) * NN + kt];
#pragma unroll
        for (int r = 0; r < 8; ++r) {
            int row = (wave << 3) + r;
            float s = 0.f;
#pragma unroll
            for (int j = 0; j < 32; ++j) s += Qs[row][j] * Ks[lane][j];
            s = s * scale + brow[(size_t)row * NN + lane];
            float mt = s;
#pragma unroll
            for (int off = 32; off; off >>= 1) mt = fmaxf(mt, __shfl_xor(mt, off));
            float mnew = fmaxf(m_i[r], mt);
            float p = __expf(s - mnew);
            float alpha = __expf(m_i[r] - mnew);
            float rs = p;
#pragma unroll
            for (int off = 32; off; off >>= 1) rs += __shfl_xor(rs, off);
            l_i[r] = l_i[r] * alpha + rs;
            m_i[r] = mnew;
            ps[wave][lane] = p;
            float accv = O_i[r] * alpha;
#pragma unroll
            for (int kk = 0; kk < 32; ++kk) accv += ps[wave][kh + kk] * Vs[kh + kk][d];
            O_i[r] = accv;
        }
    }
#pragma unroll
    for (int r = 0; r < 8; ++r) {
        float tot = O_i[r] + __shfl_xor(O_i[r], 32);
        if (lane < 32) {
            int row = q0 + (wave << 3) + r;
            o[((size_t)b * NN + row) * DD + hh * DKK + d] = tot / l_i[r];
        }
    }
}

// ---------------------------------------------------------------------------
// Fused residual + LayerNorm: h = LN(h + y) * g + b, per row of 256.
// ---------------------------------------------------------------------------
__global__ __launch_bounds__(256) void lnres_kernel(
    float* __restrict__ h, const float* __restrict__ y,
    const float* __restrict__ g, const float* __restrict__ bb)
{
    int row = blockIdx.x;
    int d = threadIdx.x;
    size_t idx = (size_t)row * DD + d;
    float val = h[idx] + y[idx];
    float s = val, s2 = val * val;
#pragma unroll
    for (int off = 32; off; off >>= 1) {
        s += __shfl_xor(s, off);
        s2 += __shfl_xor(s2, off);
    }
    __shared__ float sh[8];
    int wave = d >> 6, lane = d & 63;
    if (lane == 0) { sh[wave] = s; sh[4 + wave] = s2; }
    __syncthreads();
    if (d == 0) {
        float ts = 0.f, t2 = 0.f;
#pragma unroll
        for (int w = 0; w < 4; ++w) { ts += sh[w]; t2 += sh[4 + w]; }
        sh[0] = ts; sh[4] = t2;
    }
    __syncthreads();
    float mu = sh[0] * (1.0f / DD);
    float var = sh[4] * (1.0f / DD) - mu * mu;
    h[idx] = (val - mu) * rsqrtf(var + EPSF) * g[d] + bb[d];
}

// ---------------------------------------------------------------------------
extern "C" void kernel_launch(void* const* d_in, const int* in_sizes, int n_in,
                              void* d_out, int out_size, void* d_ws, size_t ws_size,
                              hipStream_t stream)
{
    const float* x       = (const float*)d_in[0];
    const int*   deg_in  = (const int*)d_in[1];
    const int*   deg_out = (const int*)d_in[2];
    const int*   sp      = (const int*)d_in[3];
    const float* svd     = (const float*)d_in[4];
    const float* in_emb  = (const float*)d_in[5];
    const float* out_emb = (const float*)d_in[6];
    const float* spemb   = (const float*)d_in[7];
    const float* Wsvd    = (const float*)d_in[8];
    const float* bsvd    = (const float*)d_in[9];
    const float* Wq = (const float*)d_in[10];
    const float* Wk = (const float*)d_in[11];
    const float* Wv = (const float*)d_in[12];
    const float* Wa = (const float*)d_in[13];
    const float* W1 = (const float*)d_in[14];
    const float* W2 = (const float*)d_in[15];
    const float* bq = (const float*)d_in[16];
    const float* bk = (const float*)d_in[17];
    const float* bv = (const float*)d_in[18];
    const float* ba = (const float*)d_in[19];
    const float* b1 = (const float*)d_in[20];
    const float* b2 = (const float*)d_in[21];
    const float* ln1b = (const float*)d_in[22];
    const float* ln2b = (const float*)d_in[23];
    const float* ln1g = (const float*)d_in[24];
    const float* ln2g = (const float*)d_in[25];

    float* h = (float*)d_out;
    char*  ws = (char*)d_ws;
    float* bias = (float*)ws;                        // 32 MB [H,N,N]
    float* qb   = (float*)(ws + ((size_t)32 << 20)); // 4 MB  [B,H,N,DK]
    float* kb   = (float*)(ws + ((size_t)36 << 20));
    float* vb   = (float*)(ws + ((size_t)40 << 20));
    float* ob   = (float*)(ws + ((size_t)44 << 20)); // 4 MB  [B,N,D]
    float* t1   = (float*)(ws + ((size_t)48 << 20)); // 4 MB  ffn intermediate
    float* t2   = (float*)(ws + ((size_t)52 << 20)); // 4 MB  gemm out before LN

    prologue_kernel<<<MM, 256, 0, stream>>>(x, deg_in, deg_out, svd, in_emb,
                                            out_emb, Wsvd, bsvd, h);
    bias_gather_kernel<<<(NN * NN) / 256, 256, 0, stream>>>(sp, spemb, bias);

    for (int l = 0; l < LL; ++l) {
        const size_t wo = (size_t)l * DD * DD;
        const size_t bo = (size_t)l * DD;
        gemm_qkv_kernel<<<dim3(MM / 64, DD / 64, 3), 256, 0, stream>>>(
            h, Wq + wo, Wk + wo, Wv + wo, bq + bo, bk + bo, bv + bo, qb, kb, vb);
        attn_kernel<<<dim3(NN / 32, BB * HH), 256, 0, stream>>>(qb, kb, vb, bias, ob);
        gemm_linear_kernel<0><<<dim3(MM / 64, DD / 64), 256, 0, stream>>>(
            ob, Wa + wo, ba + bo, t2);
        lnres_kernel<<<MM, 256, 0, stream>>>(h, t2, ln1g + bo, ln1b + bo);
        gemm_linear_kernel<1><<<dim3(MM / 64, DD / 64), 256, 0, stream>>>(
            h, W1 + wo, b1 + bo, t1);
        gemm_linear_kernel<0><<<dim3(MM / 64, DD / 64), 256, 0, stream>>>(
            t1, W2 + wo, b2 + bo, t2);
        lnres_kernel<<<MM, 256, 0, stream>>>(h, t2, ln2g + bo, ln2b + bo);
    }
}

// Round 2
// 613.013 us; speedup vs baseline: 7.1758x; 7.1758x over previous
//
#include <hip/hip_runtime.h>
#include <hip/hip_bf16.h>
#include <math.h>

#define NN 1024
#define BB 4
#define HH 8
#define DD 256
#define LL 4
#define DKK 32
#define MM 4096
#define EPSF 1e-6f

typedef __attribute__((ext_vector_type(8))) short short8;
typedef __attribute__((ext_vector_type(4))) float f32x4;

__device__ __forceinline__ unsigned short f2bf(float f) {
    __hip_bfloat16 h = __float2bfloat16(f);
    return *(unsigned short*)&h;
}
__device__ __forceinline__ float bf2f(unsigned short u) {
    unsigned v = ((unsigned)u) << 16;
    return __builtin_bit_cast(float, v);
}

// ---------------------------------------------------------------------------
// Prologue: h = x + in_emb[deg_in] + out_emb[deg_out] + pos @ W_svd + b_svd
// ---------------------------------------------------------------------------
__global__ __launch_bounds__(256) void prologue_kernel(
    const float* __restrict__ x, const int* __restrict__ deg_in,
    const int* __restrict__ deg_out, const float* __restrict__ svd,
    const float* __restrict__ in_emb, const float* __restrict__ out_emb,
    const float* __restrict__ Wsvd, const float* __restrict__ bsvd,
    float* __restrict__ h)
{
    int blk = blockIdx.x;            // b*N + n
    int n = blk & (NN - 1);
    int d = threadIdx.x;
    __shared__ float pos[32];
    if (d < 32) {
        float v = svd[n * 32 + d];
        pos[d] = (d < 16) ? v : -v;
    }
    __syncthreads();
    int di = deg_in[n], dou = deg_out[n];
    float acc = x[(size_t)blk * DD + d] + in_emb[(size_t)di * DD + d]
              + out_emb[(size_t)dou * DD + d] + bsvd[d];
#pragma unroll
    for (int j = 0; j < 32; ++j) acc += pos[j] * Wsvd[j * DD + d];
    h[(size_t)blk * DD + d] = acc;
}

// ---------------------------------------------------------------------------
// Spatial bias, pre-swizzled to the MFMA C-layout, bf16.
// bsw[((h*64 + q16)*16 + kt)*1024 + lane*16 + j],  j = f*4 + r
//   row = q16*16 + (lane>>4)*4 + r,  col = kt*64 + f*16 + (lane&15)
// ---------------------------------------------------------------------------
__global__ __launch_bounds__(256) void bias_swz_kernel(
    const int* __restrict__ sp, const float* __restrict__ emb,
    short* __restrict__ bsw)
{
    int t = blockIdx.x * 256 + threadIdx.x;    // t over (q16, kt, lane)
    int lane = t & 63, kt = (t >> 6) & 15, q16 = t >> 10;
    int quad = lane >> 4, c = lane & 15;
    unsigned buf[8][8];
#pragma unroll
    for (int j = 0; j < 16; ++j) {
        int f = j >> 2, r = j & 3;
        int row = q16 * 16 + quad * 4 + r;
        int col = kt * 64 + f * 16 + c;
        int p = sp[row * NN + col];
#pragma unroll
        for (int hh = 0; hh < 8; ++hh) {
            unsigned short u = f2bf(emb[p * 8 + hh]);
            if (j & 1) buf[hh][j >> 1] |= ((unsigned)u) << 16;
            else       buf[hh][j >> 1] = u;
        }
    }
#pragma unroll
    for (int hh = 0; hh < 8; ++hh) {
        uint4* dst = (uint4*)&bsw[(((size_t)hh * 64 + q16) * 16 + kt) * 1024 + (size_t)lane * 16];
        dst[0] = make_uint4(buf[hh][0], buf[hh][1], buf[hh][2], buf[hh][3]);
        dst[1] = make_uint4(buf[hh][4], buf[hh][5], buf[hh][6], buf[hh][7]);
    }
}

// ---------------------------------------------------------------------------
// fp32 GEMM  C[M,256] = A @ W + bias, optional ReLU. 64x64 tile, 4x4/thread.
// ---------------------------------------------------------------------------
template <int RELU>
__global__ __launch_bounds__(256) void gemm_linear_kernel(
    const float* __restrict__ A, const float* __restrict__ W,
    const float* __restrict__ bias, float* __restrict__ C)
{
    __shared__ float As[16][68];
    __shared__ float Bs[16][68];
    int tid = threadIdx.x;
    int tx = tid & 15, ty = tid >> 4;
    int m0 = blockIdx.x * 64;
    int n0 = blockIdx.y * 64;
    float acc[4][4] = {};
    for (int k0 = 0; k0 < 256; k0 += 16) {
#pragma unroll
        for (int i = 0; i < 4; ++i) {
            int idx = i * 256 + tid;
            int m = idx >> 4, kk = idx & 15;
            As[kk][m] = A[(size_t)(m0 + m) * DD + k0 + kk];
        }
#pragma unroll
        for (int i = 0; i < 4; ++i) {
            int idx = i * 256 + tid;
            int kk = idx >> 6, n = idx & 63;
            Bs[kk][n] = W[(size_t)(k0 + kk) * DD + n0 + n];
        }
        __syncthreads();
#pragma unroll
        for (int kk = 0; kk < 16; ++kk) {
            float4 a4 = *(const float4*)&As[kk][ty * 4];
            float4 b4 = *(const float4*)&Bs[kk][tx * 4];
            float av[4] = {a4.x, a4.y, a4.z, a4.w};
            float bv[4] = {b4.x, b4.y, b4.z, b4.w};
#pragma unroll
            for (int i = 0; i < 4; ++i)
#pragma unroll
                for (int j = 0; j < 4; ++j) acc[i][j] += av[i] * bv[j];
        }
        __syncthreads();
    }
#pragma unroll
    for (int i = 0; i < 4; ++i) {
        int m = m0 + ty * 4 + i;
#pragma unroll
        for (int j = 0; j < 4; ++j) {
            int n = n0 + tx * 4 + j;
            float v = acc[i][j] + bias[n];
            if (RELU) v = fmaxf(v, 0.f);
            C[(size_t)m * DD + n] = v;
        }
    }
}

// ---------------------------------------------------------------------------
// QKV GEMM (fp32 accumulate), bf16 outputs:
//   Q (pre-scaled by 1/sqrt(32)) and K as [B*H, N, 32]; V transposed [B*H, 32, N].
// ---------------------------------------------------------------------------
__global__ __launch_bounds__(256) void gemm_qkv_kernel(
    const float* __restrict__ A,
    const float* __restrict__ Wq, const float* __restrict__ Wk,
    const float* __restrict__ Wv,
    const float* __restrict__ bq, const float* __restrict__ bk,
    const float* __restrict__ bv,
    short* __restrict__ qo, short* __restrict__ ko, short* __restrict__ vo)
{
    int z = blockIdx.z;
    const float* W  = (z == 0) ? Wq : (z == 1) ? Wk : Wv;
    const float* bs = (z == 0) ? bq : (z == 1) ? bk : bv;

    __shared__ float As[16][68];
    __shared__ float Bs[16][68];
    int tid = threadIdx.x;
    int tx = tid & 15, ty = tid >> 4;
    int m0 = blockIdx.x * 64;
    int n0 = blockIdx.y * 64;
    float acc[4][4] = {};
    for (int k0 = 0; k0 < 256; k0 += 16) {
#pragma unroll
        for (int i = 0; i < 4; ++i) {
            int idx = i * 256 + tid;
            int m = idx >> 4, kk = idx & 15;
            As[kk][m] = A[(size_t)(m0 + m) * DD + k0 + kk];
        }
#pragma unroll
        for (int i = 0; i < 4; ++i) {
            int idx = i * 256 + tid;
            int kk = idx >> 6, n = idx & 63;
            Bs[kk][n] = W[(size_t)(k0 + kk) * DD + n0 + n];
        }
        __syncthreads();
#pragma unroll
        for (int kk = 0; kk < 16; ++kk) {
            float4 a4 = *(const float4*)&As[kk][ty * 4];
            float4 b4 = *(const float4*)&Bs[kk][tx * 4];
            float av[4] = {a4.x, a4.y, a4.z, a4.w};
            float bv[4] = {b4.x, b4.y, b4.z, b4.w};
#pragma unroll
            for (int i = 0; i < 4; ++i)
#pragma unroll
                for (int j = 0; j < 4; ++j) acc[i][j] += av[i] * bv[j];
        }
        __syncthreads();
    }

    int b = m0 >> 10;                 // 64-row tiles never straddle batch
    int nloc0 = (m0 & (NN - 1)) + ty * 4;
    int nc0 = n0 + tx * 4;            // 4-aligned, never straddles a head
    int head = nc0 >> 5, dk0 = nc0 & 31;
    int bh = b * 8 + head;

    if (z < 2) {
        const float scale = (z == 0) ? 0.17677669529663687f : 1.0f;
        short* out = (z == 0) ? qo : ko;
#pragma unroll
        for (int i = 0; i < 4; ++i) {
            int n = nloc0 + i;
            ushort4 pk;
            pk.x = f2bf((acc[i][0] + bs[nc0 + 0]) * scale);
            pk.y = f2bf((acc[i][1] + bs[nc0 + 1]) * scale);
            pk.z = f2bf((acc[i][2] + bs[nc0 + 2]) * scale);
            pk.w = f2bf((acc[i][3] + bs[nc0 + 3]) * scale);
            *(ushort4*)&out[((size_t)bh * NN + n) * DKK + dk0] = pk;
        }
    } else {
#pragma unroll
        for (int j = 0; j < 4; ++j) {
            int dk = dk0 + j;
            ushort4 pk;
            pk.x = f2bf(acc[0][j] + bs[nc0 + j]);
            pk.y = f2bf(acc[1][j] + bs[nc0 + j]);
            pk.z = f2bf(acc[2][j] + bs[nc0 + j]);
            pk.w = f2bf(acc[3][j] + bs[nc0 + j]);
            *(ushort4*)&vo[((size_t)bh * DKK + dk) * NN + nloc0] = pk;
        }
    }
}

// ---------------------------------------------------------------------------
// MFMA flash attention. q,k: bf16 [B*H,N,32] (q pre-scaled); vt: bf16 [B*H,32,N];
// bsw: swizzled bf16 bias; o: fp32 [B,N,256].
// 4 waves/block, each wave owns 16 Q rows; K-tiles of 64; no barriers.
// ---------------------------------------------------------------------------
__global__ __launch_bounds__(256) void attn_kernel(
    const short* __restrict__ q, const short* __restrict__ k,
    const short* __restrict__ vt, const short* __restrict__ bsw,
    float* __restrict__ o)
{
    int bh = blockIdx.y;
    int b = bh >> 3, h = bh & 7;
    int tid = threadIdx.x, wave = tid >> 6, lane = tid & 63;
    int quad = lane >> 4, c = lane & 15;
    int q16 = blockIdx.x * 4 + wave;     // global 16-row tile index
    int q0 = q16 * 16;

    __shared__ short Pl[4][16][72];      // per-wave P tile, padded stride 72
    short (*P)[72] = Pl[wave];

    // Q A-fragment: row = lane&15, cols quad*8..+7 (stays resident)
    short8 qf = *(const short8*)&q[((size_t)bh * NN + q0 + c) * DKK + quad * 8];

    float m_i[4], l_i[4];
    f32x4 Oa0 = {0.f, 0.f, 0.f, 0.f};
    f32x4 Oa1 = {0.f, 0.f, 0.f, 0.f};
#pragma unroll
    for (int r = 0; r < 4; ++r) { m_i[r] = -1e30f; l_i[r] = 0.f; }

    const short* bptr = &bsw[(((size_t)h * 64 + q16) * 16) * 1024 + (size_t)lane * 16];
    const f32x4 zero = {0.f, 0.f, 0.f, 0.f};

    for (int kt = 0; kt < NN; kt += 64) {
        // ---- S = Q K^T (4 MFMAs, 16x64 scores in C-layout) ----
        f32x4 s[4];
#pragma unroll
        for (int f = 0; f < 4; ++f) {
            short8 kf = *(const short8*)&k[((size_t)bh * NN + kt + f * 16 + c) * DKK + quad * 8];
            s[f] = __builtin_amdgcn_mfma_f32_16x16x32_bf16(qf, kf, zero, 0, 0, 0);
        }
        // ---- + bias (swizzled, 32B per lane) ----
        const short* bp = bptr + (size_t)(kt >> 6) * 1024;
        short8 b0 = *(const short8*)bp;
        short8 b1 = *(const short8*)(bp + 8);
#pragma unroll
        for (int f = 0; f < 4; ++f)
#pragma unroll
            for (int r = 0; r < 4; ++r) {
                int j = f * 4 + r;
                unsigned short u = (unsigned short)((j < 8) ? b0[j] : b1[j - 8]);
                s[f][r] += bf2f(u);
            }
        // ---- online softmax (row r lives in reg r; reduce over 16 lanes) ----
        float alpha[4];
#pragma unroll
        for (int r = 0; r < 4; ++r) {
            float mt = fmaxf(fmaxf(s[0][r], s[1][r]), fmaxf(s[2][r], s[3][r]));
#pragma unroll
            for (int off = 1; off < 16; off <<= 1) mt = fmaxf(mt, __shfl_xor(mt, off));
            float mn = fmaxf(m_i[r], mt);
            alpha[r] = __expf(m_i[r] - mn);
            m_i[r] = mn;
            float rs = 0.f;
#pragma unroll
            for (int f = 0; f < 4; ++f) {
                float p = __expf(s[f][r] - mn);
                s[f][r] = p;
                rs += p;
            }
#pragma unroll
            for (int off = 1; off < 16; off <<= 1) rs += __shfl_xor(rs, off);
            l_i[r] = l_i[r] * alpha[r] + rs;
            Oa0[r] *= alpha[r];
            Oa1[r] *= alpha[r];
        }
        // ---- P: C-layout -> LDS (bf16) -> A-layout ----
#pragma unroll
        for (int f = 0; f < 4; ++f)
#pragma unroll
            for (int r = 0; r < 4; ++r)
                P[quad * 4 + r][f * 16 + c] = (short)f2bf(s[f][r]);
        // ---- O += P V (4 MFMAs) ----
#pragma unroll
        for (int kc = 0; kc < 2; ++kc) {
            short8 pf = *(const short8*)&P[c][kc * 32 + quad * 8];
            short8 vf0 = *(const short8*)&vt[((size_t)bh * DKK + 0  + c) * NN + kt + kc * 32 + quad * 8];
            short8 vf1 = *(const short8*)&vt[((size_t)bh * DKK + 16 + c) * NN + kt + kc * 32 + quad * 8];
            Oa0 = __builtin_amdgcn_mfma_f32_16x16x32_bf16(pf, vf0, Oa0, 0, 0, 0);
            Oa1 = __builtin_amdgcn_mfma_f32_16x16x32_bf16(pf, vf1, Oa1, 0, 0, 0);
        }
    }
    // ---- epilogue: divide by l, store fp32 [B,N,256] ----
#pragma unroll
    for (int r = 0; r < 4; ++r) {
        float inv = 1.0f / l_i[r];
        int row = q0 + quad * 4 + r;
        float* op = &o[((size_t)b * NN + row) * DD + h * DKK];
        op[c]      = Oa0[r] * inv;
        op[16 + c] = Oa1[r] * inv;
    }
}

// ---------------------------------------------------------------------------
// Fused residual + LayerNorm
// ---------------------------------------------------------------------------
__global__ __launch_bounds__(256) void lnres_kernel(
    float* __restrict__ h, const float* __restrict__ y,
    const float* __restrict__ g, const float* __restrict__ bb)
{
    int row = blockIdx.x;
    int d = threadIdx.x;
    size_t idx = (size_t)row * DD + d;
    float val = h[idx] + y[idx];
    float s = val, s2 = val * val;
#pragma unroll
    for (int off = 32; off; off >>= 1) {
        s += __shfl_xor(s, off);
        s2 += __shfl_xor(s2, off);
    }
    __shared__ float sh[8];
    int wave = d >> 6, lane = d & 63;
    if (lane == 0) { sh[wave] = s; sh[4 + wave] = s2; }
    __syncthreads();
    if (d == 0) {
        float ts = 0.f, t2 = 0.f;
#pragma unroll
        for (int w = 0; w < 4; ++w) { ts += sh[w]; t2 += sh[4 + w]; }
        sh[0] = ts; sh[4] = t2;
    }
    __syncthreads();
    float mu = sh[0] * (1.0f / DD);
    float var = sh[4] * (1.0f / DD) - mu * mu;
    h[idx] = (val - mu) * rsqrtf(var + EPSF) * g[d] + bb[d];
}

// ---------------------------------------------------------------------------
extern "C" void kernel_launch(void* const* d_in, const int* in_sizes, int n_in,
                              void* d_out, int out_size, void* d_ws, size_t ws_size,
                              hipStream_t stream)
{
    const float* x       = (const float*)d_in[0];
    const int*   deg_in  = (const int*)d_in[1];
    const int*   deg_out = (const int*)d_in[2];
    const int*   sp      = (const int*)d_in[3];
    const float* svd     = (const float*)d_in[4];
    const float* in_emb  = (const float*)d_in[5];
    const float* out_emb = (const float*)d_in[6];
    const float* spemb   = (const float*)d_in[7];
    const float* Wsvd    = (const float*)d_in[8];
    const float* bsvd    = (const float*)d_in[9];
    const float* Wq = (const float*)d_in[10];
    const float* Wk = (const float*)d_in[11];
    const float* Wv = (const float*)d_in[12];
    const float* Wa = (const float*)d_in[13];
    const float* W1 = (const float*)d_in[14];
    const float* W2 = (const float*)d_in[15];
    const float* bq = (const float*)d_in[16];
    const float* bk = (const float*)d_in[17];
    const float* bv = (const float*)d_in[18];
    const float* ba = (const float*)d_in[19];
    const float* b1 = (const float*)d_in[20];
    const float* b2 = (const float*)d_in[21];
    const float* ln1b = (const float*)d_in[22];
    const float* ln2b = (const float*)d_in[23];
    const float* ln1g = (const float*)d_in[24];
    const float* ln2g = (const float*)d_in[25];

    float* h = (float*)d_out;
    char*  ws = (char*)d_ws;
    short* bias = (short*)ws;                         // 16 MB swizzled bf16 bias
    short* qb   = (short*)(ws + ((size_t)16 << 20));  // 2 MB bf16 [B*H,N,32]
    short* kb   = (short*)(ws + ((size_t)18 << 20));  // 2 MB
    short* vtb  = (short*)(ws + ((size_t)20 << 20));  // 2 MB bf16 [B*H,32,N]
    float* ob   = (float*)(ws + ((size_t)22 << 20));  // 4 MB fp32 [B,N,D]
    float* t1   = (float*)(ws + ((size_t)26 << 20));  // 4 MB ffn intermediate
    float* t2   = (float*)(ws + ((size_t)30 << 20));  // 4 MB pre-LN

    prologue_kernel<<<MM, 256, 0, stream>>>(x, deg_in, deg_out, svd, in_emb,
                                            out_emb, Wsvd, bsvd, h);
    bias_swz_kernel<<<256, 256, 0, stream>>>(sp, spemb, bias);

    for (int l = 0; l < LL; ++l) {
        const size_t wo = (size_t)l * DD * DD;
        const size_t bo = (size_t)l * DD;
        gemm_qkv_kernel<<<dim3(MM / 64, DD / 64, 3), 256, 0, stream>>>(
            h, Wq + wo, Wk + wo, Wv + wo, bq + bo, bk + bo, bv + bo, qb, kb, vtb);
        attn_kernel<<<dim3(NN / 64, BB * HH), 256, 0, stream>>>(qb, kb, vtb, bias, ob);
        gemm_linear_kernel<0><<<dim3(MM / 64, DD / 64), 256, 0, stream>>>(
            ob, Wa + wo, ba + bo, t2);
        lnres_kernel<<<MM, 256, 0, stream>>>(h, t2, ln1g + bo, ln1b + bo);
        gemm_linear_kernel<1><<<dim3(MM / 64, DD / 64), 256, 0, stream>>>(
            h, W1 + wo, b1 + bo, t1);
        gemm_linear_kernel<0><<<dim3(MM / 64, DD / 64), 256, 0, stream>>>(
            t1, W2 + wo, b2 + bo, t2);
        lnres_kernel<<<MM, 256, 0, stream>>>(h, t2, ln2g + bo, ln2b + bo);
    }
}

// Round 3
// 449.153 us; speedup vs baseline: 9.7937x; 1.3648x over previous
//
#include <hip/hip_runtime.h>
#include <hip/hip_bf16.h>
#include <math.h>

#define NN 1024
#define BB 4
#define HH 8
#define DD 256
#define LL 4
#define DKK 32
#define MM 4096
#define EPSF 1e-6f

typedef __attribute__((ext_vector_type(8))) short short8;
typedef __attribute__((ext_vector_type(4))) float f32x4;

__device__ __forceinline__ unsigned short f2bf(float f) {
    __hip_bfloat16 h = __float2bfloat16(f);
    return *(unsigned short*)&h;
}
__device__ __forceinline__ float bf2f(unsigned short u) {
    unsigned v = ((unsigned)u) << 16;
    return __builtin_bit_cast(float, v);
}

// ---------------------------------------------------------------------------
// Prologue: h = x + in_emb[deg_in] + out_emb[deg_out] + pos @ W_svd + b_svd
// Writes fp32 h (residual stream) and bf16 shadow h_bf (GEMM input).
// ---------------------------------------------------------------------------
__global__ __launch_bounds__(256) void prologue_kernel(
    const float* __restrict__ x, const int* __restrict__ deg_in,
    const int* __restrict__ deg_out, const float* __restrict__ svd,
    const float* __restrict__ in_emb, const float* __restrict__ out_emb,
    const float* __restrict__ Wsvd, const float* __restrict__ bsvd,
    float* __restrict__ h, short* __restrict__ hb)
{
    int blk = blockIdx.x;            // b*N + n
    int n = blk & (NN - 1);
    int d = threadIdx.x;
    __shared__ float pos[32];
    if (d < 32) {
        float v = svd[n * 32 + d];
        pos[d] = (d < 16) ? v : -v;
    }
    __syncthreads();
    int di = deg_in[n], dou = deg_out[n];
    float acc = x[(size_t)blk * DD + d] + in_emb[(size_t)di * DD + d]
              + out_emb[(size_t)dou * DD + d] + bsvd[d];
#pragma unroll
    for (int j = 0; j < 32; ++j) acc += pos[j] * Wsvd[j * DD + d];
    h[(size_t)blk * DD + d] = acc;
    hb[(size_t)blk * DD + d] = (short)f2bf(acc);
}

// ---------------------------------------------------------------------------
// Weight prep: fp32 W[L stacks][K=256][N=256] -> bf16 Wt[N][K] (transposed).
// z = name*4 + layer, name order: q,k,v,a,w1,w2.
// ---------------------------------------------------------------------------
__global__ __launch_bounds__(256) void wprep_kernel(
    const float* __restrict__ Wq, const float* __restrict__ Wk,
    const float* __restrict__ Wv, const float* __restrict__ Wa,
    const float* __restrict__ W1, const float* __restrict__ W2,
    short* __restrict__ Wt)
{
    int z = blockIdx.z;
    int name = z >> 2, layer = z & 3;
    const float* srcs[6] = {Wq, Wk, Wv, Wa, W1, W2};
    const float* W = srcs[name] + (size_t)layer * DD * DD;
    short* dst = Wt + (size_t)z * DD * DD;

    __shared__ float t[64][65];
    int tid = threadIdx.x;
    int r0 = blockIdx.x * 64, c0 = blockIdx.y * 64;
#pragma unroll
    for (int i = 0; i < 16; ++i) {
        int idx = i * 256 + tid;
        int r = idx >> 6, c = idx & 63;
        t[r][c] = W[(size_t)(r0 + r) * DD + c0 + c];
    }
    __syncthreads();
#pragma unroll
    for (int i = 0; i < 16; ++i) {
        int idx = i * 256 + tid;
        int n = idx >> 6, k = idx & 63;
        dst[(size_t)(c0 + n) * DD + r0 + k] = (short)f2bf(t[k][n]);
    }
}

// ---------------------------------------------------------------------------
// Spatial bias, pre-swizzled to the MFMA C-layout, bf16.
// ---------------------------------------------------------------------------
__global__ __launch_bounds__(256) void bias_swz_kernel(
    const int* __restrict__ sp, const float* __restrict__ emb,
    short* __restrict__ bsw)
{
    int t = blockIdx.x * 256 + threadIdx.x;    // t over (q16, kt, lane)
    int lane = t & 63, kt = (t >> 6) & 15, q16 = t >> 10;
    int quad = lane >> 4, c = lane & 15;
    unsigned buf[8][8];
#pragma unroll
    for (int j = 0; j < 16; ++j) {
        int f = j >> 2, r = j & 3;
        int row = q16 * 16 + quad * 4 + r;
        int col = kt * 64 + f * 16 + c;
        int p = sp[row * NN + col];
#pragma unroll
        for (int hh = 0; hh < 8; ++hh) {
            unsigned short u = f2bf(emb[p * 8 + hh]);
            if (j & 1) buf[hh][j >> 1] |= ((unsigned)u) << 16;
            else       buf[hh][j >> 1] = u;
        }
    }
#pragma unroll
    for (int hh = 0; hh < 8; ++hh) {
        uint4* dst = (uint4*)&bsw[(((size_t)hh * 64 + q16) * 16 + kt) * 1024 + (size_t)lane * 16];
        dst[0] = make_uint4(buf[hh][0], buf[hh][1], buf[hh][2], buf[hh][3]);
        dst[1] = make_uint4(buf[hh][4], buf[hh][5], buf[hh][6], buf[hh][7]);
    }
}

// ---------------------------------------------------------------------------
// bf16 MFMA GEMM: C[4096,256] = A_bf @ Wt_bf^T + bias.
// No LDS: A- and B-fragments are contiguous 16B global loads (Wt is [N][K]).
// 4 waves/block; wave computes 16 rows x 64 cols. Grid (64, 4).
// EPI: 0 = fp32 out, 1 = relu -> bf16 out.
// ---------------------------------------------------------------------------
template <int EPI>
__global__ __launch_bounds__(256) void gemm_bf16_kernel(
    const short* __restrict__ A, const short* __restrict__ Wt,
    const float* __restrict__ bias, float* __restrict__ outf,
    short* __restrict__ outb)
{
    int tid = threadIdx.x, wave = tid >> 6, lane = tid & 63;
    int quad = lane >> 4, c = lane & 15;
    int m0 = blockIdx.x * 64 + wave * 16;
    int n0 = blockIdx.y * 64;

    f32x4 acc[4] = {{0.f,0.f,0.f,0.f},{0.f,0.f,0.f,0.f},
                    {0.f,0.f,0.f,0.f},{0.f,0.f,0.f,0.f}};
    const short* Ap = &A[(size_t)(m0 + c) * DD];
#pragma unroll
    for (int ks = 0; ks < 8; ++ks) {
        short8 af = *(const short8*)&Ap[ks * 32 + quad * 8];
#pragma unroll
        for (int f = 0; f < 4; ++f) {
            short8 bf = *(const short8*)&Wt[(size_t)(n0 + f * 16 + c) * DD + ks * 32 + quad * 8];
            acc[f] = __builtin_amdgcn_mfma_f32_16x16x32_bf16(af, bf, acc[f], 0, 0, 0);
        }
    }
#pragma unroll
    for (int f = 0; f < 4; ++f) {
        int col = n0 + f * 16 + c;
        float bv = bias[col];
#pragma unroll
        for (int r = 0; r < 4; ++r) {
            int row = m0 + quad * 4 + r;
            float v = acc[f][r] + bv;
            if (EPI == 1) {
                v = fmaxf(v, 0.f);
                outb[(size_t)row * DD + col] = (short)f2bf(v);
            } else {
                outf[(size_t)row * DD + col] = v;
            }
        }
    }
}

// ---------------------------------------------------------------------------
// QKV bf16 GEMM: z picks q/k/v. Q pre-scaled; Q,K -> [B*H,N,32]; V -> [B*H,32,N].
// ---------------------------------------------------------------------------
__global__ __launch_bounds__(256) void gemm_qkv_kernel(
    const short* __restrict__ A,
    const short* __restrict__ Wtq, const short* __restrict__ Wtk,
    const short* __restrict__ Wtv,
    const float* __restrict__ bq, const float* __restrict__ bk,
    const float* __restrict__ bv,
    short* __restrict__ qo, short* __restrict__ ko, short* __restrict__ vo)
{
    int z = blockIdx.z;
    const short* Wt = (z == 0) ? Wtq : (z == 1) ? Wtk : Wtv;
    const float* bs = (z == 0) ? bq : (z == 1) ? bk : bv;

    int tid = threadIdx.x, wave = tid >> 6, lane = tid & 63;
    int quad = lane >> 4, c = lane & 15;
    int m0 = blockIdx.x * 64 + wave * 16;
    int n0 = blockIdx.y * 64;

    f32x4 acc[4] = {{0.f,0.f,0.f,0.f},{0.f,0.f,0.f,0.f},
                    {0.f,0.f,0.f,0.f},{0.f,0.f,0.f,0.f}};
    const short* Ap = &A[(size_t)(m0 + c) * DD];
#pragma unroll
    for (int ks = 0; ks < 8; ++ks) {
        short8 af = *(const short8*)&Ap[ks * 32 + quad * 8];
#pragma unroll
        for (int f = 0; f < 4; ++f) {
            short8 bf = *(const short8*)&Wt[(size_t)(n0 + f * 16 + c) * DD + ks * 32 + quad * 8];
            acc[f] = __builtin_amdgcn_mfma_f32_16x16x32_bf16(af, bf, acc[f], 0, 0, 0);
        }
    }

    int b = m0 >> 10;
    int tok0 = (m0 & (NN - 1)) + quad * 4;
    const float scale = 0.17677669529663687f;   // 1/sqrt(32)

#pragma unroll
    for (int f = 0; f < 4; ++f) {
        int col = n0 + f * 16 + c;
        int head = col >> 5, dk = col & 31;
        int bh = b * 8 + head;
        float bv2 = bs[col];
        if (z == 2) {
            ushort4 pk;
            pk.x = f2bf(acc[f][0] + bv2);
            pk.y = f2bf(acc[f][1] + bv2);
            pk.z = f2bf(acc[f][2] + bv2);
            pk.w = f2bf(acc[f][3] + bv2);
            *(ushort4*)&vo[((size_t)bh * DKK + dk) * NN + tok0] = pk;
        } else {
            short* out = (z == 0) ? qo : ko;
            float sc = (z == 0) ? scale : 1.0f;
#pragma unroll
            for (int r = 0; r < 4; ++r)
                out[((size_t)bh * NN + tok0 + r) * DKK + dk] =
                    (short)f2bf((acc[f][r] + bv2) * sc);
        }
    }
}

// ---------------------------------------------------------------------------
// MFMA flash attention (unchanged core); output now bf16 [B,N,256].
// ---------------------------------------------------------------------------
__global__ __launch_bounds__(256) void attn_kernel(
    const short* __restrict__ q, const short* __restrict__ k,
    const short* __restrict__ vt, const short* __restrict__ bsw,
    short* __restrict__ o)
{
    int bh = blockIdx.y;
    int b = bh >> 3, h = bh & 7;
    int tid = threadIdx.x, wave = tid >> 6, lane = tid & 63;
    int quad = lane >> 4, c = lane & 15;
    int q16 = blockIdx.x * 4 + wave;
    int q0 = q16 * 16;

    __shared__ short Pl[4][16][72];
    short (*P)[72] = Pl[wave];

    short8 qf = *(const short8*)&q[((size_t)bh * NN + q0 + c) * DKK + quad * 8];

    float m_i[4], l_i[4];
    f32x4 Oa0 = {0.f, 0.f, 0.f, 0.f};
    f32x4 Oa1 = {0.f, 0.f, 0.f, 0.f};
#pragma unroll
    for (int r = 0; r < 4; ++r) { m_i[r] = -1e30f; l_i[r] = 0.f; }

    const short* bptr = &bsw[(((size_t)h * 64 + q16) * 16) * 1024 + (size_t)lane * 16];
    const f32x4 zero = {0.f, 0.f, 0.f, 0.f};

    for (int kt = 0; kt < NN; kt += 64) {
        f32x4 s[4];
#pragma unroll
        for (int f = 0; f < 4; ++f) {
            short8 kf = *(const short8*)&k[((size_t)bh * NN + kt + f * 16 + c) * DKK + quad * 8];
            s[f] = __builtin_amdgcn_mfma_f32_16x16x32_bf16(qf, kf, zero, 0, 0, 0);
        }
        const short* bp = bptr + (size_t)(kt >> 6) * 1024;
        short8 b0 = *(const short8*)bp;
        short8 b1 = *(const short8*)(bp + 8);
#pragma unroll
        for (int f = 0; f < 4; ++f)
#pragma unroll
            for (int r = 0; r < 4; ++r) {
                int j = f * 4 + r;
                unsigned short u = (unsigned short)((j < 8) ? b0[j] : b1[j - 8]);
                s[f][r] += bf2f(u);
            }
        float alpha[4];
#pragma unroll
        for (int r = 0; r < 4; ++r) {
            float mt = fmaxf(fmaxf(s[0][r], s[1][r]), fmaxf(s[2][r], s[3][r]));
#pragma unroll
            for (int off = 1; off < 16; off <<= 1) mt = fmaxf(mt, __shfl_xor(mt, off));
            float mn = fmaxf(m_i[r], mt);
            alpha[r] = __expf(m_i[r] - mn);
            m_i[r] = mn;
            float rs = 0.f;
#pragma unroll
            for (int f = 0; f < 4; ++f) {
                float p = __expf(s[f][r] - mn);
                s[f][r] = p;
                rs += p;
            }
#pragma unroll
            for (int off = 1; off < 16; off <<= 1) rs += __shfl_xor(rs, off);
            l_i[r] = l_i[r] * alpha[r] + rs;
            Oa0[r] *= alpha[r];
            Oa1[r] *= alpha[r];
        }
#pragma unroll
        for (int f = 0; f < 4; ++f)
#pragma unroll
            for (int r = 0; r < 4; ++r)
                P[quad * 4 + r][f * 16 + c] = (short)f2bf(s[f][r]);
#pragma unroll
        for (int kc = 0; kc < 2; ++kc) {
            short8 pf = *(const short8*)&P[c][kc * 32 + quad * 8];
            short8 vf0 = *(const short8*)&vt[((size_t)bh * DKK + 0  + c) * NN + kt + kc * 32 + quad * 8];
            short8 vf1 = *(const short8*)&vt[((size_t)bh * DKK + 16 + c) * NN + kt + kc * 32 + quad * 8];
            Oa0 = __builtin_amdgcn_mfma_f32_16x16x32_bf16(pf, vf0, Oa0, 0, 0, 0);
            Oa1 = __builtin_amdgcn_mfma_f32_16x16x32_bf16(pf, vf1, Oa1, 0, 0, 0);
        }
    }
#pragma unroll
    for (int r = 0; r < 4; ++r) {
        float inv = 1.0f / l_i[r];
        int row = q0 + quad * 4 + r;
        short* op = &o[((size_t)b * NN + row) * DD + h * DKK];
        op[c]      = (short)f2bf(Oa0[r] * inv);
        op[16 + c] = (short)f2bf(Oa1[r] * inv);
    }
}

// ---------------------------------------------------------------------------
// Fused residual + LayerNorm; writes fp32 h and bf16 shadow.
// ---------------------------------------------------------------------------
__global__ __launch_bounds__(256) void lnres_kernel(
    float* __restrict__ h, short* __restrict__ hb, const float* __restrict__ y,
    const float* __restrict__ g, const float* __restrict__ bb)
{
    int row = blockIdx.x;
    int d = threadIdx.x;
    size_t idx = (size_t)row * DD + d;
    float val = h[idx] + y[idx];
    float s = val, s2 = val * val;
#pragma unroll
    for (int off = 32; off; off >>= 1) {
        s += __shfl_xor(s, off);
        s2 += __shfl_xor(s2, off);
    }
    __shared__ float sh[8];
    int wave = d >> 6, lane = d & 63;
    if (lane == 0) { sh[wave] = s; sh[4 + wave] = s2; }
    __syncthreads();
    if (d == 0) {
        float ts = 0.f, t2 = 0.f;
#pragma unroll
        for (int w = 0; w < 4; ++w) { ts += sh[w]; t2 += sh[4 + w]; }
        sh[0] = ts; sh[4] = t2;
    }
    __syncthreads();
    float mu = sh[0] * (1.0f / DD);
    float var = sh[4] * (1.0f / DD) - mu * mu;
    float res = (val - mu) * rsqrtf(var + EPSF) * g[d] + bb[d];
    h[idx] = res;
    hb[idx] = (short)f2bf(res);
}

// ---------------------------------------------------------------------------
extern "C" void kernel_launch(void* const* d_in, const int* in_sizes, int n_in,
                              void* d_out, int out_size, void* d_ws, size_t ws_size,
                              hipStream_t stream)
{
    const float* x       = (const float*)d_in[0];
    const int*   deg_in  = (const int*)d_in[1];
    const int*   deg_out = (const int*)d_in[2];
    const int*   sp      = (const int*)d_in[3];
    const float* svd     = (const float*)d_in[4];
    const float* in_emb  = (const float*)d_in[5];
    const float* out_emb = (const float*)d_in[6];
    const float* spemb   = (const float*)d_in[7];
    const float* Wsvd    = (const float*)d_in[8];
    const float* bsvd    = (const float*)d_in[9];
    const float* Wq = (const float*)d_in[10];
    const float* Wk = (const float*)d_in[11];
    const float* Wv = (const float*)d_in[12];
    const float* Wa = (const float*)d_in[13];
    const float* W1 = (const float*)d_in[14];
    const float* W2 = (const float*)d_in[15];
    const float* bq = (const float*)d_in[16];
    const float* bk = (const float*)d_in[17];
    const float* bv = (const float*)d_in[18];
    const float* ba = (const float*)d_in[19];
    const float* b1 = (const float*)d_in[20];
    const float* b2 = (const float*)d_in[21];
    const float* ln1b = (const float*)d_in[22];
    const float* ln2b = (const float*)d_in[23];
    const float* ln1g = (const float*)d_in[24];
    const float* ln2g = (const float*)d_in[25];

    float* h = (float*)d_out;
    char*  ws = (char*)d_ws;
    short* bias = (short*)ws;                         // 16 MB swizzled bf16 bias
    short* qb   = (short*)(ws + ((size_t)16 << 20));  // 2 MB bf16 [B*H,N,32]
    short* kb   = (short*)(ws + ((size_t)18 << 20));  // 2 MB
    short* vtb  = (short*)(ws + ((size_t)20 << 20));  // 2 MB bf16 [B*H,32,N]
    short* obb  = (short*)(ws + ((size_t)22 << 20));  // 2 MB bf16 attn out
    short* t1   = (short*)(ws + ((size_t)24 << 20));  // 2 MB bf16 relu out
    float* t2   = (float*)(ws + ((size_t)26 << 20));  // 4 MB fp32 pre-LN
    short* hb   = (short*)(ws + ((size_t)30 << 20));  // 2 MB bf16 shadow of h
    short* Wt   = (short*)(ws + ((size_t)32 << 20));  // 3 MB bf16 transposed W

    prologue_kernel<<<MM, 256, 0, stream>>>(x, deg_in, deg_out, svd, in_emb,
                                            out_emb, Wsvd, bsvd, h, hb);
    wprep_kernel<<<dim3(4, 4, 24), 256, 0, stream>>>(Wq, Wk, Wv, Wa, W1, W2, Wt);
    bias_swz_kernel<<<256, 256, 0, stream>>>(sp, spemb, bias);

    const size_t WSZ = (size_t)DD * DD;
    for (int l = 0; l < LL; ++l) {
        const size_t bo = (size_t)l * DD;
        const short* Wtq = Wt + (0 * 4 + l) * WSZ;
        const short* Wtk = Wt + (1 * 4 + l) * WSZ;
        const short* Wtv = Wt + (2 * 4 + l) * WSZ;
        const short* Wta = Wt + (3 * 4 + l) * WSZ;
        const short* Wt1 = Wt + (4 * 4 + l) * WSZ;
        const short* Wt2 = Wt + (5 * 4 + l) * WSZ;

        gemm_qkv_kernel<<<dim3(MM / 64, DD / 64, 3), 256, 0, stream>>>(
            hb, Wtq, Wtk, Wtv, bq + bo, bk + bo, bv + bo, qb, kb, vtb);
        attn_kernel<<<dim3(NN / 64, BB * HH), 256, 0, stream>>>(qb, kb, vtb, bias, obb);
        gemm_bf16_kernel<0><<<dim3(MM / 64, DD / 64), 256, 0, stream>>>(
            obb, Wta, ba + bo, t2, nullptr);
        lnres_kernel<<<MM, 256, 0, stream>>>(h, hb, t2, ln1g + bo, ln1b + bo);
        gemm_bf16_kernel<1><<<dim3(MM / 64, DD / 64), 256, 0, stream>>>(
            hb, Wt1, b1 + bo, nullptr, t1);
        gemm_bf16_kernel<0><<<dim3(MM / 64, DD / 64), 256, 0, stream>>>(
            t1, Wt2, b2 + bo, t2, nullptr);
        lnres_kernel<<<MM, 256, 0, stream>>>(h, hb, t2, ln2g + bo, ln2b + bo);
    }
}